// Round 21
// baseline (199.024 us; speedup 1.0000x reference)
//
#include <hip/hip_runtime.h>
#include <cstdint>
#include <cstddef>

typedef __attribute__((ext_vector_type(4))) float f32x4;
typedef __attribute__((ext_vector_type(8))) short s16x8;
typedef __attribute__((ext_vector_type(4))) short s16x4;

#define B_  2
#define T_  2048
#define C_  2048
#define H_  16
#define KV_ 4
#define D_  128
#define M_  4096   // B*T

static __device__ __forceinline__ float bf2f(ushort u){
  union { float f; uint32_t u; } x; x.u = ((uint32_t)u) << 16; return x.f;
}
static __device__ __forceinline__ ushort f2bf(float f){
  union { float f; uint32_t u; } x; x.f = f;
  uint32_t r = x.u + 0x7FFF + ((x.u >> 16) & 1);
  return (ushort)(r >> 16);
}

// async global->LDS, 16B per lane; dest = wave-uniform base + lane*16
static __device__ __forceinline__ void gl_lds16(const ushort* g, ushort* s){
  __builtin_amdgcn_global_load_lds((const __attribute__((address_space(1))) void*)g,
                                   (__attribute__((address_space(3))) void*)s, 16, 0, 0);
}

// ---------------- fp32 -> bf16 elementwise ----------------
__global__ void cvt_f32_bf16(const float* __restrict__ in, ushort* __restrict__ out, int n4){
  int idx = blockIdx.x * blockDim.x + threadIdx.x;
  int stride = gridDim.x * blockDim.x;
  for (int i = idx; i < n4; i += stride){
    float4 v = ((const float4*)in)[i];
    s16x4 o;
    o[0] = (short)f2bf(v.x); o[1] = (short)f2bf(v.y);
    o[2] = (short)f2bf(v.z); o[3] = (short)f2bf(v.w);
    ((s16x4*)out)[i] = o;
  }
}

// ---------------- fused weight transposes: fp32 [2048][N] -> bf16 [N][2048] ----------------
// Q/K segments are row-PERMUTED within each 128-row head block so the rope pair
// (d=i, d=i+64) lands in the SAME lane's two n-fragments:
//   dst = ((d&63)>>4)*32 + ((d>>6)&1)*16 + (d&15)
__global__ void transpose_all(const float* __restrict__ Wq, const float* __restrict__ Wk,
                              const float* __restrict__ Wv, const float* __restrict__ Wo,
                              ushort* __restrict__ Wcat, ushort* __restrict__ Wot){
  __shared__ float tile[32][33];
  int bx = blockIdx.x;
  const float* W; ushort* Wt; int N; int n0; bool perm;
  if (bx < 64)      { W = Wq; Wt = Wcat;                          N = 2048; n0 = bx * 32;        perm = true;  }
  else if (bx < 80) { W = Wk; Wt = Wcat + (size_t)2048 * 2048;    N = 512;  n0 = (bx - 64) * 32; perm = true;  }
  else if (bx < 96) { W = Wv; Wt = Wcat + (size_t)2560 * 2048;    N = 512;  n0 = (bx - 80) * 32; perm = false; }
  else              { W = Wo; Wt = Wot;                           N = 2048; n0 = (bx - 96) * 32; perm = false; }
  int k0 = blockIdx.y * 32;
  int tx = threadIdx.x, ty = threadIdx.y;   // 32 x 8
  #pragma unroll
  for (int r = 0; r < 4; r++)
    tile[ty + 8*r][tx] = W[(size_t)(k0 + ty + 8*r) * N + n0 + tx];
  __syncthreads();
  #pragma unroll
  for (int r = 0; r < 4; r++){
    int nn = n0 + ty + 8*r;                 // source col index
    int dd = nn & 127;
    int dst_in = (((dd & 63) >> 4) << 5) | (((dd >> 6) & 1) << 4) | (dd & 15);
    int dst = perm ? ((nn & ~127) | dst_in) : nn;
    Wt[(size_t)dst * 2048 + k0 + tx] = f2bf(tile[tx][ty + 8*r]);
  }
}

// ---------------- deep-pipelined GEMM (R11-proven) + fused in-lane RoPE epilogue ----------------
// MODE 0: fp32 out row-major [M,N]. MODE 1: QKV scatter (N=3072) with RoPE
// applied in-register to Q (scale sq) and K (scale 1); pair in same lane.
template<int MODE>
__global__ __launch_bounds__(512)
void gemm_deep(const ushort* __restrict__ A, const ushort* __restrict__ Bt,
               void* __restrict__ C0, void* __restrict__ C1, void* __restrict__ C2,
               int N, int Kd, int nbx, float sq){
  __shared__ __align__(16) ushort Abuf[4][8192];   // [buf][128 rows x 64 k]
  __shared__ __align__(16) ushort Bbuf[4][8192];
  int tid = threadIdx.x, w = tid >> 6, l = tid & 63;
  int l15 = l & 15, l4 = l >> 4;

  int cpx = gridDim.x >> 3;
  int logical = (blockIdx.x & 7) * cpx + (blockIdx.x >> 3);
  int bx = logical % nbx, by = logical / nbx;
  int rblk = by * 128, cblk = bx * 128;
  int wm = w & 1, wn = w >> 1;

  int sr = tid >> 3;
  int sc = ((tid & 7) * 8) ^ ((sr & 7) << 3);
  const ushort* gA = A  + (size_t)(rblk + sr) * Kd + sc;
  const ushort* gB = Bt + (size_t)(cblk + sr) * Kd + sc;
  size_t rowK = (size_t)64 * Kd;
  int wb = w * 512;

  auto stage = [&](int t){
    int bsel = t & 3; int koff = t * 64;
    gl_lds16(gA + koff,        &Abuf[bsel][wb]);
    gl_lds16(gA + rowK + koff, &Abuf[bsel][4096 + wb]);
    gl_lds16(gB + koff,        &Bbuf[bsel][wb]);
    gl_lds16(gB + rowK + koff, &Bbuf[bsel][4096 + wb]);
  };

  int arow = wm * 64 + l15;
  int brow = wn * 32 + l15;
  int kx0 = (l4 * 8) ^ ((l15 & 7) << 3);
  int kx1 = (32 + l4 * 8) ^ ((l15 & 7) << 3);

  f32x4 acc[4][2] = {};

  auto phase = [&](int t, int dostage, int vm){
    const ushort* Ab = Abuf[t & 3];
    const ushort* Bb = Bbuf[t & 3];
    s16x8 a[4][2], b[2][2];
    #pragma unroll
    for (int m = 0; m < 4; m++){
      a[m][0] = *(const s16x8*)(Ab + (arow + m*16) * 64 + kx0);
      a[m][1] = *(const s16x8*)(Ab + (arow + m*16) * 64 + kx1);
    }
    #pragma unroll
    for (int n = 0; n < 2; n++){
      b[n][0] = *(const s16x8*)(Bb + (brow + n*16) * 64 + kx0);
      b[n][1] = *(const s16x8*)(Bb + (brow + n*16) * 64 + kx1);
    }
    if (dostage) stage(t + 3);
    if (vm == 8)      { asm volatile("s_waitcnt vmcnt(8)" ::: "memory"); }
    else if (vm == 4) { asm volatile("s_waitcnt vmcnt(4)" ::: "memory"); }
    else if (vm == 0) { asm volatile("s_waitcnt vmcnt(0)" ::: "memory"); }
    asm volatile("s_waitcnt lgkmcnt(0)" ::: "memory");
    __builtin_amdgcn_sched_barrier(0);
    __builtin_amdgcn_s_barrier();
    __builtin_amdgcn_s_setprio(1);
    #pragma unroll
    for (int m = 0; m < 4; m++)
      #pragma unroll
      for (int n = 0; n < 2; n++){
        acc[m][n] = __builtin_amdgcn_mfma_f32_16x16x32_bf16(a[m][0], b[n][0], acc[m][n], 0, 0, 0);
        acc[m][n] = __builtin_amdgcn_mfma_f32_16x16x32_bf16(a[m][1], b[n][1], acc[m][n], 0, 0, 0);
      }
    __builtin_amdgcn_s_setprio(0);
  };

  stage(0); stage(1); stage(2);
  asm volatile("s_waitcnt vmcnt(8)" ::: "memory");
  __builtin_amdgcn_s_barrier();

  int nt = Kd >> 6;                                // 32
  #pragma unroll 1
  for (int t = 0; t < nt - 3; ++t) phase(t, 1, 8);
  phase(nt - 3, 0, 4);
  phase(nt - 2, 0, 0);
  phase(nt - 1, 0, -1);

  if (MODE == 0){
    #pragma unroll
    for (int m = 0; m < 4; m++)
      #pragma unroll
      for (int n = 0; n < 2; n++)
        #pragma unroll
        for (int j = 0; j < 4; j++){
          int row = rblk + wm*64 + m*16 + l4*4 + j;
          int col = cblk + wn*32 + n*16 + l15;
          ((float*)C0)[(size_t)row * N + col] = acc[m][n][j];
        }
  } else if (cblk < 2560){
    // fused in-lane RoPE: this lane holds d=i (n=0) and d=i+64 (n=1), i const
    float scale = (cblk < 2048) ? sq : 1.0f;
    int hh = (cblk < 2048) ? (cblk >> 7) : ((cblk - 2048) >> 7);
    int nh = (cblk < 2048) ? H_ : KV_;
    ushort* base = (ushort*)((cblk < 2048) ? C0 : C1);
    int i = wn * 16 + l15;
    float invf = exp2f(-(float)i * 0.2076205059304602f);   // log2(10000)/64
    #pragma unroll
    for (int m = 0; m < 4; m++){
      #pragma unroll
      for (int j = 0; j < 4; j++){
        int row = rblk + wm*64 + m*16 + l4*4 + j;
        int t = row & (T_ - 1), bb = row >> 11;
        float s, co;
        __sincosf((float)t * invf, &s, &co);
        float v0 = acc[m][0][j], v1 = acc[m][1][j];
        size_t roff = (((size_t)(bb * nh + hh)) * T_ + t) * D_;
        base[roff + i]      = f2bf((v0 * co - v1 * s) * scale);
        base[roff + i + 64] = f2bf((v1 * co + v0 * s) * scale);
      }
    }
  } else {
    // V: transpose-scatter, unpermuted
    #pragma unroll
    for (int m = 0; m < 4; m++)
      #pragma unroll
      for (int n = 0; n < 2; n++)
        #pragma unroll
        for (int j = 0; j < 4; j++){
          int row = rblk + wm*64 + m*16 + l4*4 + j;
          int col = cblk + wn*32 + n*16 + l15;
          int t = row & (T_ - 1), bb = row >> 11;
          int c2 = col - 2560;
          int hh = c2 >> 7, d = c2 & 127;
          ((ushort*)C2)[(((size_t)(bb * KV_ + hh)) * D_ + d) * T_ + t] = f2bf(acc[m][n][j]);
        }
  }
}

// ---------------- causal GQA flash attention v8: one-tile software pipeline ----------------
// 3-buffer K/V LDS (112KB, 1 block/CU). Iter t: write(t); barrier; QK(t) [MFMA]
// overlaps softmax(t-1)+P+PV(t-1) [VALU/LDS]. Race ledger: writer of buf[t%3]
// sits after barrier(t-1); last readers (QK(t-3) in iter t-3, PV(t-3) in iter
// t-2) complete before any wave reaches barrier(t-1). Mask only in epilogue.
__global__ __launch_bounds__(512, 1)
void attn_kernel8(const ushort* __restrict__ Q, const ushort* __restrict__ Kc,
                  const ushort* __restrict__ Vt, ushort* __restrict__ O){
  __shared__ __align__(16) ushort Ks[3][64 * 128];   // swizzled: col ^= (row&7)<<3
  __shared__ __align__(16) ushort Vs[3][128 * 64];   // swizzled
  __shared__ __align__(16) ushort Ps[8 * 16 * 64];   // per-wave P^T, swizzled
  int bid = blockIdx.x;
  int i  = bid >> 3;
  int qt = (i < 32) ? (63 - i) : (i - 32);   // balanced ordering
  int sub = bid & 7;
  int b = sub >> 2, kvh = sub & 3;
  int tid = threadIdx.x, w = tid >> 6, l = tid & 63;
  int l15 = l & 15, l4 = l >> 4;
  int sw3 = (l15 & 7) << 3;
  int q0 = qt * 32;
  int hq = kvh * 4 + (w >> 1);
  int qrow0 = q0 + (w & 1) * 16;
  int qrow = qrow0 + l15;

  s16x8 qf[4];
  const ushort* qbase = Q + (((size_t)(b * H_ + hq)) * T_ + qrow) * D_;
  #pragma unroll
  for (int kk = 0; kk < 4; kk++)
    qf[kk] = *(const s16x8*)(qbase + kk * 32 + l4 * 8);

  f32x4 oacc[8] = {};
  float mrun = -1e30f;
  float rsum = 0.f;
  const float THR = 11.5415603f;             // 8 * log2(e)
  ushort* Pw = Ps + w * (16 * 64) + l15 * 64;

  const ushort* kbase = Kc + ((size_t)(b * KV_ + kvh)) * T_ * D_;
  const ushort* vbase = Vt + ((size_t)(b * KV_ + kvh)) * D_ * T_;
  int jmax = (q0 + 31) >> 6;

  int kr0 = tid >> 4, kcb = tid & 15;
  int vd0 = tid >> 3, vtb = tid & 7;
  int ksoff = kr0 * 128 + ((kcb * 8) ^ ((kr0 & 7) << 3));
  int vsoff = vd0 * 64  + ((vtb * 8) ^ ((vd0 & 7) << 3));
  const ushort* kg = kbase + (size_t)kr0 * D_ + kcb * 8;
  const ushort* vg = vbase + (size_t)vd0 * T_ + vtb * 8;

  s16x8 kreg0, kreg1, vreg0, vreg1;
  kreg0 = *(const s16x8*)(kg);
  kreg1 = *(const s16x8*)(kg + (size_t)32 * D_);
  vreg0 = *(const s16x8*)(vg);
  vreg1 = *(const s16x8*)(vg + (size_t)64 * T_);

  // QK^T of tile from Ks buffer 'sel' into sacc
  auto qk = [&](int sel, f32x4 (&sacc)[4]){
    const ushort* Ksc = Ks[sel];
    __builtin_amdgcn_s_setprio(1);
    #pragma unroll
    for (int kk = 0; kk < 4; kk++){
      #pragma unroll
      for (int n = 0; n < 4; n++){
        s16x8 kf = *(const s16x8*)(Ksc + (16*n + l15) * 128 + ((kk*32 + l4*8) ^ sw3));
        sacc[n] = __builtin_amdgcn_mfma_f32_16x16x32_bf16(kf, qf[kk], sacc[n], 0, 0, 0);
      }
    }
    __builtin_amdgcn_s_setprio(0);
  };

  // softmax + P pack + PV for a finished tile (V in buffer 'vsel')
  auto smpv = [&](f32x4 (&sacc)[4], int vsel){
    const ushort* Vsc = Vs[vsel];
    float mloc = -1e30f;
    #pragma unroll
    for (int n = 0; n < 4; n++)
      #pragma unroll
      for (int j = 0; j < 4; j++)
        mloc = fmaxf(mloc, sacc[n][j]);
    if (__any((int)(mloc > mrun + THR))){
      float m2 = fmaxf(mloc, __shfl_xor(mloc, 16));
      m2 = fmaxf(m2, __shfl_xor(m2, 32));
      float mnew = fmaxf(mrun, m2);
      float alpha = exp2f(mrun - mnew);
      mrun = mnew;
      rsum *= alpha;
      #pragma unroll
      for (int n8 = 0; n8 < 8; n8++)
        #pragma unroll
        for (int j = 0; j < 4; j++)
          oacc[n8][j] *= alpha;
    }
    #pragma unroll
    for (int n = 0; n < 4; n++){
      float p0 = exp2f(sacc[n][0] - mrun);
      float p1 = exp2f(sacc[n][1] - mrun);
      float p2 = exp2f(sacc[n][2] - mrun);
      float p3 = exp2f(sacc[n][3] - mrun);
      rsum += (p0 + p1) + (p2 + p3);
      uint32_t lo, hi;
      asm volatile("v_cvt_pk_bf16_f32 %0, %1, %2" : "=v"(lo) : "v"(p0), "v"(p1));
      asm volatile("v_cvt_pk_bf16_f32 %0, %1, %2" : "=v"(hi) : "v"(p2), "v"(p3));
      uint2 pk; pk.x = lo; pk.y = hi;
      *(uint2*)(Pw + ((16*n + 4*l4) ^ sw3)) = pk;
    }
    __builtin_amdgcn_s_setprio(1);
    #pragma unroll
    for (int kk = 0; kk < 2; kk++){
      s16x8 pf = *(const s16x8*)(Pw + ((kk*32 + l4*8) ^ sw3));
      #pragma unroll
      for (int n8 = 0; n8 < 8; n8++){
        s16x8 vf = *(const s16x8*)(Vsc + (16*n8 + l15) * 64 + ((kk*32 + l4*8) ^ sw3));
        oacc[n8] = __builtin_amdgcn_mfma_f32_16x16x32_bf16(vf, pf, oacc[n8], 0, 0, 0);
      }
    }
    __builtin_amdgcn_s_setprio(0);
  };

  // prologue: stage tile 0; QK(0) -> sp
  {
    ushort* Ksc = Ks[0]; ushort* Vsc = Vs[0];
    *(s16x8*)(Ksc + ksoff)            = kreg0;
    *(s16x8*)(Ksc + ksoff + 32 * 128) = kreg1;
    *(s16x8*)(Vsc + vsoff)            = vreg0;
    *(s16x8*)(Vsc + vsoff + 64 * 64)  = vreg1;
    __syncthreads();
  }
  f32x4 sp[4] = {};
  qk(0, sp);
  if (jmax > 0){
    kreg0 = *(const s16x8*)(kg + (size_t)64 * D_);
    kreg1 = *(const s16x8*)(kg + (size_t)96 * D_);
    vreg0 = *(const s16x8*)(vg + 64);
    vreg1 = *(const s16x8*)(vg + (size_t)64 * T_ + 64);
  }

  #pragma unroll 1
  for (int t = 1; t <= jmax; ++t){
    int sel = t % 3;
    ushort* Ksc = Ks[sel]; ushort* Vsc = Vs[sel];
    *(s16x8*)(Ksc + ksoff)            = kreg0;
    *(s16x8*)(Ksc + ksoff + 32 * 128) = kreg1;
    *(s16x8*)(Vsc + vsoff)            = vreg0;
    *(s16x8*)(Vsc + vsoff + 64 * 64)  = vreg1;
    __syncthreads();
    f32x4 scur[4] = {};
    qk(sel, scur);                           // MFMA pipe: tile t
    smpv(sp, (t - 1) % 3);                   // VALU/LDS pipes: tile t-1
    if (t < jmax){
      int k1 = (t + 1) * 64;
      kreg0 = *(const s16x8*)(kg + (size_t)k1 * D_);
      kreg1 = *(const s16x8*)(kg + (size_t)(k1 + 32) * D_);
      vreg0 = *(const s16x8*)(vg + k1);
      vreg1 = *(const s16x8*)(vg + (size_t)64 * T_ + k1);
    }
    #pragma unroll
    for (int n = 0; n < 4; n++) sp[n] = scur[n];
  }

  // epilogue: tile jmax is the diagonal tile -> mask, then softmax+PV
  {
    int k0 = jmax * 64;
    #pragma unroll
    for (int n = 0; n < 4; n++)
      #pragma unroll
      for (int j = 0; j < 4; j++){
        int kcol = k0 + 16*n + 4*l4 + j;
        if (kcol > qrow) sp[n][j] = -1e30f;
      }
    smpv(sp, jmax % 3);
  }

  rsum += __shfl_xor(rsum, 16);
  rsum += __shfl_xor(rsum, 32);
  float inv = 1.f / rsum;
  ushort* obase = O + ((size_t)(b * T_ + qrow)) * C_ + hq * D_ + 4*l4;
  #pragma unroll
  for (int n8 = 0; n8 < 8; n8++){
    s16x4 ov;
    #pragma unroll
    for (int j = 0; j < 4; j++)
      ov[j] = (short)f2bf(oacc[n8][j] * inv);
    *(s16x4*)(obase + 16*n8) = ov;
  }
}

// ---------------- launch ----------------
extern "C" void kernel_launch(void* const* d_in, const int* in_sizes, int n_in,
                              void* d_out, int out_size, void* d_ws, size_t ws_size,
                              hipStream_t stream){
  const float* x  = (const float*)d_in[0];
  const float* Wq = (const float*)d_in[1];
  const float* Wk = (const float*)d_in[2];
  const float* Wv = (const float*)d_in[3];
  const float* Wo = (const float*)d_in[4];
  float* out = (float*)d_out;

  char* ws = (char*)d_ws;
  size_t off = 0;
  auto alloc = [&](size_t bytes)->void*{
    void* p = ws + off; off += (bytes + 255) & ~(size_t)255; return p;
  };
  ushort* xb   = (ushort*)alloc((size_t)M_ * C_ * 2);
  ushort* Wcat = (ushort*)alloc((size_t)3072 * 2048 * 2);   // [Wq|Wk|Wv]^T rows (Q/K perm'd)
  ushort* Wot  = (ushort*)alloc((size_t)2048 * 2048 * 2);
  ushort* Qb   = (ushort*)alloc((size_t)B_ * H_ * T_ * D_ * 2);
  ushort* Kb   = (ushort*)alloc((size_t)B_ * KV_ * T_ * D_ * 2);
  ushort* Vtb  = (ushort*)alloc((size_t)B_ * KV_ * T_ * D_ * 2);
  ushort* Ob   = (ushort*)alloc((size_t)M_ * C_ * 2);

  cvt_f32_bf16<<<2048, 256, 0, stream>>>(x, xb, M_ * C_ / 4);
  transpose_all<<<dim3(160, 64), dim3(32, 8), 0, stream>>>(Wq, Wk, Wv, Wo, Wcat, Wot);

  // fused QKV projection + in-lane RoPE: 128x128 tiles, 768 blocks
  // Q scale folds D^-0.5 and log2(e) (attn softmax runs in exp2 domain)
  gemm_deep<1><<<768, 512, 0, stream>>>(xb, Wcat, Qb, Kb, Vtb, 3072, 2048, 24,
                                        0.08838834764831845f * 1.4426950408889634f);

  attn_kernel8<<<512, 512, 0, stream>>>(Qb, Kb, Vtb, Ob);

  // output projection: [4096,2048] x [2048,2048]^T -> fp32, 512 blocks
  gemm_deep<0><<<512, 512, 0, stream>>>(Ob, Wot, out, nullptr, nullptr, 2048, 2048, 16, 0.f);
}

// Round 22
// 183.991 us; speedup vs baseline: 1.0817x; 1.0817x over previous
//
#include <hip/hip_runtime.h>
#include <cstdint>
#include <cstddef>

typedef __attribute__((ext_vector_type(4))) float f32x4;
typedef __attribute__((ext_vector_type(8))) short s16x8;
typedef __attribute__((ext_vector_type(4))) short s16x4;

#define B_  2
#define T_  2048
#define C_  2048
#define H_  16
#define KV_ 4
#define D_  128
#define M_  4096   // B*T

static __device__ __forceinline__ float bf2f(ushort u){
  union { float f; uint32_t u; } x; x.u = ((uint32_t)u) << 16; return x.f;
}
static __device__ __forceinline__ ushort f2bf(float f){
  union { float f; uint32_t u; } x; x.f = f;
  uint32_t r = x.u + 0x7FFF + ((x.u >> 16) & 1);
  return (ushort)(r >> 16);
}

// async global->LDS, 16B per lane; dest = wave-uniform base + lane*16
static __device__ __forceinline__ void gl_lds16(const ushort* g, ushort* s){
  __builtin_amdgcn_global_load_lds((const __attribute__((address_space(1))) void*)g,
                                   (__attribute__((address_space(3))) void*)s, 16, 0, 0);
}

// ---------------- fp32 -> bf16 elementwise ----------------
__global__ void cvt_f32_bf16(const float* __restrict__ in, ushort* __restrict__ out, int n4){
  int idx = blockIdx.x * blockDim.x + threadIdx.x;
  int stride = gridDim.x * blockDim.x;
  for (int i = idx; i < n4; i += stride){
    float4 v = ((const float4*)in)[i];
    s16x4 o;
    o[0] = (short)f2bf(v.x); o[1] = (short)f2bf(v.y);
    o[2] = (short)f2bf(v.z); o[3] = (short)f2bf(v.w);
    ((s16x4*)out)[i] = o;
  }
}

// ---------------- fused weight transposes: fp32 [2048][N] -> bf16 [N][2048] ----------------
// Q/K segments are row-PERMUTED within each 128-row head block so the rope pair
// (d=i, d=i+64) lands in the SAME lane's two n-fragments:
//   dst = ((d&63)>>4)*32 + ((d>>6)&1)*16 + (d&15)
__global__ void transpose_all(const float* __restrict__ Wq, const float* __restrict__ Wk,
                              const float* __restrict__ Wv, const float* __restrict__ Wo,
                              ushort* __restrict__ Wcat, ushort* __restrict__ Wot){
  __shared__ float tile[32][33];
  int bx = blockIdx.x;
  const float* W; ushort* Wt; int N; int n0; bool perm;
  if (bx < 64)      { W = Wq; Wt = Wcat;                          N = 2048; n0 = bx * 32;        perm = true;  }
  else if (bx < 80) { W = Wk; Wt = Wcat + (size_t)2048 * 2048;    N = 512;  n0 = (bx - 64) * 32; perm = true;  }
  else if (bx < 96) { W = Wv; Wt = Wcat + (size_t)2560 * 2048;    N = 512;  n0 = (bx - 80) * 32; perm = false; }
  else              { W = Wo; Wt = Wot;                           N = 2048; n0 = (bx - 96) * 32; perm = false; }
  int k0 = blockIdx.y * 32;
  int tx = threadIdx.x, ty = threadIdx.y;   // 32 x 8
  #pragma unroll
  for (int r = 0; r < 4; r++)
    tile[ty + 8*r][tx] = W[(size_t)(k0 + ty + 8*r) * N + n0 + tx];
  __syncthreads();
  #pragma unroll
  for (int r = 0; r < 4; r++){
    int nn = n0 + ty + 8*r;                 // source col index
    int dd = nn & 127;
    int dst_in = (((dd & 63) >> 4) << 5) | (((dd >> 6) & 1) << 4) | (dd & 15);
    int dst = perm ? ((nn & ~127) | dst_in) : nn;
    Wt[(size_t)dst * 2048 + k0 + tx] = f2bf(tile[tx][ty + 8*r]);
  }
}

// ---------------- deep-pipelined GEMM (R11-proven) + fused in-lane RoPE epilogue ----------------
// MODE 0: fp32 out row-major [M,N]. MODE 1: QKV scatter (N=3072) with RoPE
// applied in-register to Q (scale sq) and K (scale 1); pair in same lane.
template<int MODE>
__global__ __launch_bounds__(512)
void gemm_deep(const ushort* __restrict__ A, const ushort* __restrict__ Bt,
               void* __restrict__ C0, void* __restrict__ C1, void* __restrict__ C2,
               int N, int Kd, int nbx, float sq){
  __shared__ __align__(16) ushort Abuf[4][8192];   // [buf][128 rows x 64 k]
  __shared__ __align__(16) ushort Bbuf[4][8192];
  int tid = threadIdx.x, w = tid >> 6, l = tid & 63;
  int l15 = l & 15, l4 = l >> 4;

  int cpx = gridDim.x >> 3;
  int logical = (blockIdx.x & 7) * cpx + (blockIdx.x >> 3);
  int bx = logical % nbx, by = logical / nbx;
  int rblk = by * 128, cblk = bx * 128;
  int wm = w & 1, wn = w >> 1;

  int sr = tid >> 3;
  int sc = ((tid & 7) * 8) ^ ((sr & 7) << 3);
  const ushort* gA = A  + (size_t)(rblk + sr) * Kd + sc;
  const ushort* gB = Bt + (size_t)(cblk + sr) * Kd + sc;
  size_t rowK = (size_t)64 * Kd;
  int wb = w * 512;

  auto stage = [&](int t){
    int bsel = t & 3; int koff = t * 64;
    gl_lds16(gA + koff,        &Abuf[bsel][wb]);
    gl_lds16(gA + rowK + koff, &Abuf[bsel][4096 + wb]);
    gl_lds16(gB + koff,        &Bbuf[bsel][wb]);
    gl_lds16(gB + rowK + koff, &Bbuf[bsel][4096 + wb]);
  };

  int arow = wm * 64 + l15;
  int brow = wn * 32 + l15;
  int kx0 = (l4 * 8) ^ ((l15 & 7) << 3);
  int kx1 = (32 + l4 * 8) ^ ((l15 & 7) << 3);

  f32x4 acc[4][2] = {};

  auto phase = [&](int t, int dostage, int vm){
    const ushort* Ab = Abuf[t & 3];
    const ushort* Bb = Bbuf[t & 3];
    s16x8 a[4][2], b[2][2];
    #pragma unroll
    for (int m = 0; m < 4; m++){
      a[m][0] = *(const s16x8*)(Ab + (arow + m*16) * 64 + kx0);
      a[m][1] = *(const s16x8*)(Ab + (arow + m*16) * 64 + kx1);
    }
    #pragma unroll
    for (int n = 0; n < 2; n++){
      b[n][0] = *(const s16x8*)(Bb + (brow + n*16) * 64 + kx0);
      b[n][1] = *(const s16x8*)(Bb + (brow + n*16) * 64 + kx1);
    }
    if (dostage) stage(t + 3);
    if (vm == 8)      { asm volatile("s_waitcnt vmcnt(8)" ::: "memory"); }
    else if (vm == 4) { asm volatile("s_waitcnt vmcnt(4)" ::: "memory"); }
    else if (vm == 0) { asm volatile("s_waitcnt vmcnt(0)" ::: "memory"); }
    asm volatile("s_waitcnt lgkmcnt(0)" ::: "memory");
    __builtin_amdgcn_sched_barrier(0);
    __builtin_amdgcn_s_barrier();
    __builtin_amdgcn_s_setprio(1);
    #pragma unroll
    for (int m = 0; m < 4; m++)
      #pragma unroll
      for (int n = 0; n < 2; n++){
        acc[m][n] = __builtin_amdgcn_mfma_f32_16x16x32_bf16(a[m][0], b[n][0], acc[m][n], 0, 0, 0);
        acc[m][n] = __builtin_amdgcn_mfma_f32_16x16x32_bf16(a[m][1], b[n][1], acc[m][n], 0, 0, 0);
      }
    __builtin_amdgcn_s_setprio(0);
  };

  stage(0); stage(1); stage(2);
  asm volatile("s_waitcnt vmcnt(8)" ::: "memory");
  __builtin_amdgcn_s_barrier();

  int nt = Kd >> 6;                                // 32
  #pragma unroll 1
  for (int t = 0; t < nt - 3; ++t) phase(t, 1, 8);
  phase(nt - 3, 0, 4);
  phase(nt - 2, 0, 0);
  phase(nt - 1, 0, -1);

  if (MODE == 0){
    #pragma unroll
    for (int m = 0; m < 4; m++)
      #pragma unroll
      for (int n = 0; n < 2; n++)
        #pragma unroll
        for (int j = 0; j < 4; j++){
          int row = rblk + wm*64 + m*16 + l4*4 + j;
          int col = cblk + wn*32 + n*16 + l15;
          ((float*)C0)[(size_t)row * N + col] = acc[m][n][j];
        }
  } else if (cblk < 2560){
    // fused in-lane RoPE: this lane holds d=i (n=0) and d=i+64 (n=1), i const
    float scale = (cblk < 2048) ? sq : 1.0f;
    int hh = (cblk < 2048) ? (cblk >> 7) : ((cblk - 2048) >> 7);
    int nh = (cblk < 2048) ? H_ : KV_;
    ushort* base = (ushort*)((cblk < 2048) ? C0 : C1);
    int i = wn * 16 + l15;
    float invf = exp2f(-(float)i * 0.2076205059304602f);   // log2(10000)/64
    #pragma unroll
    for (int m = 0; m < 4; m++){
      #pragma unroll
      for (int j = 0; j < 4; j++){
        int row = rblk + wm*64 + m*16 + l4*4 + j;
        int t = row & (T_ - 1), bb = row >> 11;
        float s, co;
        __sincosf((float)t * invf, &s, &co);
        float v0 = acc[m][0][j], v1 = acc[m][1][j];
        size_t roff = (((size_t)(bb * nh + hh)) * T_ + t) * D_;
        base[roff + i]      = f2bf((v0 * co - v1 * s) * scale);
        base[roff + i + 64] = f2bf((v1 * co + v0 * s) * scale);
      }
    }
  } else {
    // V: transpose-scatter, unpermuted
    #pragma unroll
    for (int m = 0; m < 4; m++)
      #pragma unroll
      for (int n = 0; n < 2; n++)
        #pragma unroll
        for (int j = 0; j < 4; j++){
          int row = rblk + wm*64 + m*16 + l4*4 + j;
          int col = cblk + wn*32 + n*16 + l15;
          int t = row & (T_ - 1), bb = row >> 11;
          int c2 = col - 2560;
          int hh = c2 >> 7, d = c2 & 127;
          ((ushort*)C2)[(((size_t)(bb * KV_ + hh)) * D_ + d) * T_ + t] = f2bf(acc[m][n][j]);
        }
  }
}

// ---------------- causal GQA flash attention v7: double-buffered K/V, 1 barrier/tile ----------------
// Ledger: wave A writes buf[(t+1)&1] only after passing barrier(t); all waves reach
// barrier(t) only after their write(t), which follows their compute(t-1) -- the last
// reader of buf[(t+1)&1] (= buf[(t-1)&1]). Single barrier per tile is race-free.
__global__ __launch_bounds__(512, 4)
void attn_kernel7(const ushort* __restrict__ Q, const ushort* __restrict__ Kc,
                  const ushort* __restrict__ Vt, ushort* __restrict__ O){
  __shared__ __align__(16) ushort Ks[2][64 * 128];   // swizzled: col ^= (row&7)<<3
  __shared__ __align__(16) ushort Vs[2][128 * 64];   // swizzled
  __shared__ __align__(16) ushort Ps[8 * 16 * 64];   // per-wave P^T [q=16][k=64], swizzled
  int bid = blockIdx.x;
  int i  = bid >> 3;
  int qt = (i < 32) ? (63 - i) : (i - 32);   // balanced pairing per CU
  int sub = bid & 7;
  int b = sub >> 2, kvh = sub & 3;
  int tid = threadIdx.x, w = tid >> 6, l = tid & 63;
  int l15 = l & 15, l4 = l >> 4;
  int sw3 = (l15 & 7) << 3;                  // read/write-side swizzle (ushort units)
  int q0 = qt * 32;
  int hq = kvh * 4 + (w >> 1);
  int qrow0 = q0 + (w & 1) * 16;
  int qrow = qrow0 + l15;                    // this lane's q-row

  s16x8 qf[4];
  const ushort* qbase = Q + (((size_t)(b * H_ + hq)) * T_ + qrow) * D_;
  #pragma unroll
  for (int kk = 0; kk < 4; kk++)
    qf[kk] = *(const s16x8*)(qbase + kk * 32 + l4 * 8);

  f32x4 oacc[8] = {};
  float mrun = -1e30f;
  float rsum = 0.f;
  const float THR = 11.5415603f;             // 8 * log2(e)
  ushort* Pw = Ps + w * (16 * 64) + l15 * 64;

  const ushort* kbase = Kc + ((size_t)(b * KV_ + kvh)) * T_ * D_;
  const ushort* vbase = Vt + ((size_t)(b * KV_ + kvh)) * D_ * T_;
  int jmax = (q0 + 31) >> 6;

  int kr0 = tid >> 4, kcb = tid & 15;
  int vd0 = tid >> 3, vtb = tid & 7;
  int ksoff = kr0 * 128 + ((kcb * 8) ^ ((kr0 & 7) << 3));
  int vsoff = vd0 * 64  + ((vtb * 8) ^ ((vd0 & 7) << 3));
  const ushort* kg = kbase + (size_t)kr0 * D_ + kcb * 8;
  const ushort* vg = vbase + (size_t)vd0 * T_ + vtb * 8;

  s16x8 kreg0, kreg1, vreg0, vreg1;
  kreg0 = *(const s16x8*)(kg);
  kreg1 = *(const s16x8*)(kg + (size_t)32 * D_);
  vreg0 = *(const s16x8*)(vg);
  vreg1 = *(const s16x8*)(vg + (size_t)64 * T_);

  for (int jt = 0; jt <= jmax; jt++){
    ushort* Ksc = Ks[jt & 1];
    ushort* Vsc = Vs[jt & 1];
    *(s16x8*)(Ksc + ksoff)            = kreg0;
    *(s16x8*)(Ksc + ksoff + 32 * 128) = kreg1;
    *(s16x8*)(Vsc + vsoff)            = vreg0;
    *(s16x8*)(Vsc + vsoff + 64 * 64)  = vreg1;
    __syncthreads();                       // writes visible; prev buffer free next iter
    if (jt < jmax){
      int k1 = (jt + 1) * 64;
      kreg0 = *(const s16x8*)(kg + (size_t)k1 * D_);
      kreg1 = *(const s16x8*)(kg + (size_t)(k1 + 32) * D_);
      vreg0 = *(const s16x8*)(vg + k1);
      vreg1 = *(const s16x8*)(vg + (size_t)64 * T_ + k1);
    }
    int k0 = jt * 64;

    f32x4 sacc[4] = {};
    __builtin_amdgcn_s_setprio(1);
    #pragma unroll
    for (int kk = 0; kk < 4; kk++){
      #pragma unroll
      for (int n = 0; n < 4; n++){
        s16x8 kf = *(const s16x8*)(Ksc + (16*n + l15) * 128 + ((kk*32 + l4*8) ^ sw3));
        sacc[n] = __builtin_amdgcn_mfma_f32_16x16x32_bf16(kf, qf[kk], sacc[n], 0, 0, 0);
      }
    }
    __builtin_amdgcn_s_setprio(0);
    if (jt == jmax){
      #pragma unroll
      for (int n = 0; n < 4; n++)
        #pragma unroll
        for (int j = 0; j < 4; j++){
          int kcol = k0 + 16*n + 4*l4 + j;
          if (kcol > qrow) sacc[n][j] = -1e30f;
        }
    }
    float mloc = -1e30f;
    #pragma unroll
    for (int n = 0; n < 4; n++)
      #pragma unroll
      for (int j = 0; j < 4; j++)
        mloc = fmaxf(mloc, sacc[n][j]);
    if (__any((int)(mloc > mrun + THR))){
      float m2 = fmaxf(mloc, __shfl_xor(mloc, 16));
      m2 = fmaxf(m2, __shfl_xor(m2, 32));
      float mnew = fmaxf(mrun, m2);
      float alpha = exp2f(mrun - mnew);
      mrun = mnew;
      rsum *= alpha;
      #pragma unroll
      for (int n8 = 0; n8 < 8; n8++)
        #pragma unroll
        for (int j = 0; j < 4; j++)
          oacc[n8][j] *= alpha;
    }
    #pragma unroll
    for (int n = 0; n < 4; n++){
      float p0 = exp2f(sacc[n][0] - mrun);
      float p1 = exp2f(sacc[n][1] - mrun);
      float p2 = exp2f(sacc[n][2] - mrun);
      float p3 = exp2f(sacc[n][3] - mrun);
      rsum += (p0 + p1) + (p2 + p3);
      uint32_t lo, hi;
      asm volatile("v_cvt_pk_bf16_f32 %0, %1, %2" : "=v"(lo) : "v"(p0), "v"(p1));
      asm volatile("v_cvt_pk_bf16_f32 %0, %1, %2" : "=v"(hi) : "v"(p2), "v"(p3));
      uint2 pk; pk.x = lo; pk.y = hi;
      *(uint2*)(Pw + ((16*n + 4*l4) ^ sw3)) = pk;
    }
    __builtin_amdgcn_s_setprio(1);
    #pragma unroll
    for (int kk = 0; kk < 2; kk++){
      s16x8 pf = *(const s16x8*)(Pw + ((kk*32 + l4*8) ^ sw3));
      #pragma unroll
      for (int n8 = 0; n8 < 8; n8++){
        s16x8 vf = *(const s16x8*)(Vsc + (16*n8 + l15) * 64 + ((kk*32 + l4*8) ^ sw3));
        oacc[n8] = __builtin_amdgcn_mfma_f32_16x16x32_bf16(vf, pf, oacc[n8], 0, 0, 0);
      }
    }
    __builtin_amdgcn_s_setprio(0);
  }

  rsum += __shfl_xor(rsum, 16);
  rsum += __shfl_xor(rsum, 32);
  float inv = 1.f / rsum;
  ushort* obase = O + ((size_t)(b * T_ + qrow)) * C_ + hq * D_ + 4*l4;
  #pragma unroll
  for (int n8 = 0; n8 < 8; n8++){
    s16x4 ov;
    #pragma unroll
    for (int j = 0; j < 4; j++)
      ov[j] = (short)f2bf(oacc[n8][j] * inv);
    *(s16x4*)(obase + 16*n8) = ov;
  }
}

// ---------------- launch ----------------
extern "C" void kernel_launch(void* const* d_in, const int* in_sizes, int n_in,
                              void* d_out, int out_size, void* d_ws, size_t ws_size,
                              hipStream_t stream){
  const float* x  = (const float*)d_in[0];
  const float* Wq = (const float*)d_in[1];
  const float* Wk = (const float*)d_in[2];
  const float* Wv = (const float*)d_in[3];
  const float* Wo = (const float*)d_in[4];
  float* out = (float*)d_out;

  char* ws = (char*)d_ws;
  size_t off = 0;
  auto alloc = [&](size_t bytes)->void*{
    void* p = ws + off; off += (bytes + 255) & ~(size_t)255; return p;
  };
  ushort* xb   = (ushort*)alloc((size_t)M_ * C_ * 2);
  ushort* Wcat = (ushort*)alloc((size_t)3072 * 2048 * 2);   // [Wq|Wk|Wv]^T rows (Q/K perm'd)
  ushort* Wot  = (ushort*)alloc((size_t)2048 * 2048 * 2);
  ushort* Qb   = (ushort*)alloc((size_t)B_ * H_ * T_ * D_ * 2);
  ushort* Kb   = (ushort*)alloc((size_t)B_ * KV_ * T_ * D_ * 2);
  ushort* Vtb  = (ushort*)alloc((size_t)B_ * KV_ * T_ * D_ * 2);
  ushort* Ob   = (ushort*)alloc((size_t)M_ * C_ * 2);

  cvt_f32_bf16<<<2048, 256, 0, stream>>>(x, xb, M_ * C_ / 4);
  transpose_all<<<dim3(160, 64), dim3(32, 8), 0, stream>>>(Wq, Wk, Wv, Wo, Wcat, Wot);

  // fused QKV projection + in-lane RoPE: 128x128 tiles, 768 blocks
  // Q scale folds D^-0.5 and log2(e) (attn softmax runs in exp2 domain)
  gemm_deep<1><<<768, 512, 0, stream>>>(xb, Wcat, Qb, Kb, Vtb, 3072, 2048, 24,
                                        0.08838834764831845f * 1.4426950408889634f);

  attn_kernel7<<<512, 512, 0, stream>>>(Qb, Kb, Vtb, Ob);

  // output projection: [4096,2048] x [2048,2048]^T -> fp32, 512 blocks
  gemm_deep<0><<<512, 512, 0, stream>>>(Ob, Wot, out, nullptr, nullptr, 2048, 2048, 16, 0.f);
}